// Round 7
// baseline (512.004 us; speedup 1.0000x reference)
//
#include <hip/hip_runtime.h>
#include <math.h>

#ifndef M_PI
#define M_PI 3.14159265358979323846
#endif

constexpr int S_LEN    = 176400;
constexpr int NFFT     = 2048;
constexpr int NC       = 1024;
constexpr int HOP_     = 441;
constexpr int T_FRAMES = 401;
constexpr int F_BINS   = 1025;
constexpr int F_STRIDE = 1028;     // fp32 spec row stride (16B aligned)
constexpr int N_CH     = 64;
constexpr float EPS_   = 1e-8f;
constexpr float C1_    = 0.0004f;
constexpr float C2_    = 0.0036f;
constexpr float COV_NORM_ = 49.0f / 48.0f;

constexpr int WINP_OFF = 0;        // float2[1024]  window pairs
constexpr int TG1_OFF  = 2048;     // float2[16*64] w1024^(L*k1) [k1][L]
constexpr int TG2_OFF  = 4096;     // float2[16*4]  w64^(n3*k2)  [k2][n3]
constexpr int UTW_OFF  = 4224;     // float2[1025]
constexpr int SPEC_OFF = 6400;
constexpr int RPB_     = 10;
constexpr int N_CHUNKS = 40;

#define WAVE_SYNC() asm volatile("s_waitcnt lgkmcnt(0)" ::: "memory")

__device__ __forceinline__ float2 cadd(float2 a, float2 b){ return make_float2(a.x+b.x, a.y+b.y); }
__device__ __forceinline__ float2 csub(float2 a, float2 b){ return make_float2(a.x-b.x, a.y-b.y); }
__device__ __forceinline__ float2 cmul(float2 a, float2 b){ return make_float2(a.x*b.x-a.y*b.y, a.x*b.y+a.y*b.x); }
__device__ __forceinline__ float2 mulnegi(float2 v){ return make_float2(v.y, -v.x); }  // -i*v

__device__ __constant__ float2 W16C[10] = {
    { 1.0f, 0.0f},
    { 0.92387953251128674f, -0.38268343236508978f},
    { 0.70710678118654752f, -0.70710678118654752f},
    { 0.38268343236508978f, -0.92387953251128674f},
    { 0.0f, -1.0f},
    {-0.38268343236508978f, -0.92387953251128674f},
    {-0.70710678118654752f, -0.70710678118654752f},
    {-0.92387953251128674f, -0.38268343236508978f},
    {-1.0f, 0.0f},
    {-0.92387953251128674f,  0.38268343236508978f},
};

// 16-pt DFT in registers (natural order in/out)
__device__ __forceinline__ void fft16(float2 (&r)[16]) {
    float2 C[4][4];
    #pragma unroll
    for (int m2 = 0; m2 < 4; ++m2) {
        float2 u0 = r[m2], u1 = r[4+m2], u2 = r[8+m2], u3 = r[12+m2];
        float2 t0 = cadd(u0,u2), t1 = csub(u0,u2), t2 = cadd(u1,u3), t3 = csub(u1,u3);
        C[0][m2] = cadd(t0,t2);
        C[1][m2] = cadd(t1, mulnegi(t3));
        C[2][m2] = csub(t0,t2);
        C[3][m2] = csub(t1, mulnegi(t3));
    }
    #pragma unroll
    for (int a = 0; a < 4; ++a) {
        float2 u0 = C[a][0];
        float2 u1 = (a == 0) ? C[a][1] : cmul(C[a][1], W16C[a]);
        float2 u2 = (a == 0) ? C[a][2] : cmul(C[a][2], W16C[2*a]);
        float2 u3 = (a == 0) ? C[a][3] : cmul(C[a][3], W16C[3*a]);
        float2 t0 = cadd(u0,u2), t1 = csub(u0,u2), t2 = cadd(u1,u3), t3 = csub(u1,u3);
        r[a]      = cadd(t0,t2);
        r[a+4]    = cadd(t1, mulnegi(t3));
        r[a+8]    = csub(t0,t2);
        r[a+12]   = csub(t1, mulnegi(t3));
    }
}

__global__ __launch_bounds__(256) void init_tables_kernel(float* __restrict__ ws, float* __restrict__ out) {
    const int idx = blockIdx.x * 256 + threadIdx.x;
    if (idx < 64) out[idx] = 0.0f;
    if (idx < 1024) {
        float w0 = 0.5f - 0.5f * cosf((float)(2.0 * M_PI / NFFT) * (float)(2*idx));
        float w1 = 0.5f - 0.5f * cosf((float)(2.0 * M_PI / NFFT) * (float)(2*idx+1));
        ws[WINP_OFF + 2*idx]   = w0;
        ws[WINP_OFF + 2*idx+1] = w1;
    }
    if (idx < 1024) {
        int k1 = idx >> 6, L = idx & 63;
        float ang = -2.0f * (float)M_PI * (float)(L * k1) / (float)NC;
        float s, c; sincosf(ang, &s, &c);
        ws[TG1_OFF + 2*idx] = c; ws[TG1_OFF + 2*idx+1] = s;
    }
    if (idx < 64) {
        int k2 = idx >> 2, n3 = idx & 3;
        float ang = -2.0f * (float)M_PI * (float)(n3 * k2) / 64.0f;
        float s, c; sincosf(ang, &s, &c);
        ws[TG2_OFF + 2*idx] = c; ws[TG2_OFF + 2*idx+1] = s;
    }
    if (idx < F_BINS) {
        float ang = -(float)M_PI * (float)idx / (float)NC;
        float s, c; sincosf(ang, &s, &c);
        ws[UTW_OFF + 2*idx] = c; ws[UTW_OFF + 2*idx+1] = s;
    }
}

// One WAVE per 1024-pt FFT; 2 waves/block. float2 XOR-swizzled LDS transposes
// (R5 layout: measured 0 bank conflicts), fp32 forward-only stores.
// 16 KB LDS/block -> ~10 blocks/CU with 128-thread blocks.
__global__ __launch_bounds__(128, 5) void stft_mag_kernel(
    const float* __restrict__ x0, const float* __restrict__ x1,
    float* __restrict__ ws, int ch0, int nch, int swizzle)
{
    __shared__ float2 lds[2][1024];

    const int tid  = threadIdx.x;
    const int wave = tid >> 6;
    const int L    = tid & 63;

    int ch, pair, which;
    if (swizzle) {
        int g = blockIdx.x;
        ch    = ch0 + (g & 7) * 8 + ((g >> 3) & 7);
        which = (g >> 6) & 1;
        pair  = g >> 7;
    } else {
        int bx = blockIdx.x;
        which = bx / 201;
        pair  = bx - which * 201;
        ch    = ch0 + blockIdx.y;
    }
    const int t = 2 * pair + wave;
    if (t > 400) return;                 // no block barriers; safe to exit

    const float* __restrict__ xin = (which ? x1 : x0) + (size_t)ch * S_LEN;
    const float2* __restrict__ winp = (const float2*)(ws + WINP_OFF);
    const float2* __restrict__ tg1  = (const float2*)(ws + TG1_OFF);
    const float2* __restrict__ tg2  = (const float2*)(ws + TG2_OFF);
    const float2* __restrict__ utw  = (const float2*)(ws + UTW_OFF);
    float2* B = lds[wave];

    // ---- load comb + window: r[n1] = (x[2c]w[2c], x[2c+1]w[2c+1]), c = 64*n1 + L
    float2 r[16];
    const int base = t * HOP_ - 1024;
    #pragma unroll
    for (int j = 0; j < 16; ++j) {
        const int s0 = base + 128 * j;           // wave-uniform span start
        const int i0 = s0 + 2 * L;
        float2 wp = winp[(j << 6) + L];
        float a, b;
        if (s0 >= 0 && s0 + 128 <= S_LEN) {
            a = xin[i0]; b = xin[i0 + 1];
        } else {
            int ia = i0;     ia = (ia < 0) ? -ia : ia; ia = (ia >= S_LEN) ? 2*S_LEN-2-ia : ia;
            int ib = i0 + 1; ib = (ib < 0) ? -ib : ib; ib = (ib >= S_LEN) ? 2*S_LEN-2-ib : ib;
            a = xin[ia]; b = xin[ib];
        }
        r[j] = make_float2(a * wp.x, b * wp.y);
    }

    // ---- stage 1: fft16 over n1 + twiddle w1024^{L*k1}; XOR-swizzled store
    fft16(r);
    #pragma unroll
    for (int k1 = 0; k1 < 16; ++k1) {
        float2 v = (k1 == 0) ? r[0] : cmul(r[k1], tg1[(k1 << 6) + L]);
        B[(L << 4) + (k1 ^ (L & 15))] = v;
    }
    WAVE_SYNC();

    // ---- stage 2: thread (k1 = L&15, n3 = L>>4); fft16 over n2 + twiddle w64^{n3*k2}
    {
        const int k1 = L & 15, n3 = L >> 4;
        float2 s[16];
        #pragma unroll
        for (int n2 = 0; n2 < 16; ++n2) {
            int lr = (n2 << 2) + n3;
            s[n2] = B[(lr << 4) + (k1 ^ (lr & 15))];
        }
        fft16(s);
        #pragma unroll
        for (int k2 = 1; k2 < 16; ++k2) s[k2] = cmul(s[k2], tg2[(k2 << 2) + n3]);
        WAVE_SYNC();
        #pragma unroll
        for (int k2 = 0; k2 < 16; ++k2) B[(k2 << 6) + L] = s[k2];
    }
    WAVE_SYNC();

    // ---- stage 3: thread (k1b = L&15, g4 = L>>4) holds k2 = 4*g4+rr; 4-pt over n3
    {
        const int g4 = L >> 4, k1b = L & 15;
        float2 D[4][4];
        #pragma unroll
        for (int rr = 0; rr < 4; ++rr)
            #pragma unroll
            for (int n3 = 0; n3 < 4; ++n3)
                D[rr][n3] = B[(g4 << 8) + (rr << 6) + (n3 << 4) + k1b];
        WAVE_SYNC();
        #pragma unroll
        for (int rr = 0; rr < 4; ++rr) {
            float2 e0 = cadd(D[rr][0], D[rr][2]);
            float2 e1 = csub(D[rr][0], D[rr][2]);
            float2 e2 = cadd(D[rr][1], D[rr][3]);
            float2 e3 = csub(D[rr][1], D[rr][3]);
            int kb = k1b + (g4 << 6) + (rr << 4);
            B[kb]       = cadd(e0, e2);
            B[kb + 256] = cadd(e1, mulnegi(e3));
            B[kb + 512] = csub(e0, e2);
            B[kb + 768] = csub(e1, mulnegi(e3));
        }
    }
    WAVE_SYNC();

    // ---- real-FFT unpack + magnitude + fp32 forward stores
    {
        float* __restrict__ sout =
            ws + SPEC_OFF + ((size_t)which * nch + (size_t)(ch - ch0)) * (size_t)T_FRAMES * F_STRIDE
                          + (size_t)t * F_STRIDE;
        #pragma unroll
        for (int j = 0; j < 17; ++j) {
            int m = (j << 6) + L;
            if (j < 16 || L == 0) {
                float2 Zr = B[m & 1023];
                float2 Zn = B[(1024 - m) & 1023];
                float Ex = 0.5f * (Zr.x + Zn.x);
                float Ey = 0.5f * (Zr.y - Zn.y);
                float Ox = 0.5f * (Zr.y + Zn.y);
                float Oy = 0.5f * (Zn.x - Zr.x);
                float2 wu = utw[m];
                float Xx = Ex + wu.x * Ox - wu.y * Oy;
                float Xy = Ey + wu.x * Oy + wu.y * Ox;
                sout[m] = sqrtf(fmaxf(Xx * Xx + Xy * Xy, EPS_));
            }
        }
    }
}

// SSIM: thread owns 4 consecutive cols; float4 global loads; rolling vertical sums;
// 5 scalar LDS arrays, lane stride 5 words -> conflict-free (proven R5).
__global__ __launch_bounds__(256) void ssim_kernel(
    const float* __restrict__ ws, float* __restrict__ out,
    int ch0, int nch)
{
    __shared__ float csx[1284], csy[1284], csxx[1284], csyy[1284], csxy[1284];
    __shared__ double red[256];

    const int tid = threadIdx.x;
    const int cg  = blockIdx.y;
    const int ch  = ch0 + cg;
    const float* __restrict__ spec = ws + SPEC_OFF;
    const size_t per_ch = (size_t)T_FRAMES * F_STRIDE;
    const float* __restrict__ X = spec + (size_t)cg * per_ch;
    const float* __restrict__ Y = spec + ((size_t)nch + cg) * per_ch;

    const int t_begin = 3 + blockIdx.x * RPB_;
    const int t_end_  = min(t_begin + RPB_, T_FRAMES - 3);

    const int fv = tid << 2;
    const bool last = (tid == 255);
    const float inv49 = 1.0f / 49.0f;
    double acc = 0.0;

    float sx[4] = {0,0,0,0}, sy[4] = {0,0,0,0}, sxx[4] = {0,0,0,0},
          syy[4] = {0,0,0,0}, sxy[4] = {0,0,0,0};
    float s5[5] = {0,0,0,0,0};

    for (int rr = t_begin - 3; rr < t_begin + 3; ++rr) {
        float4 xv = *(const float4*)(X + (size_t)rr * F_STRIDE + fv);
        float4 yv = *(const float4*)(Y + (size_t)rr * F_STRIDE + fv);
        float xa[4] = {xv.x, xv.y, xv.z, xv.w}, ya[4] = {yv.x, yv.y, yv.z, yv.w};
        #pragma unroll
        for (int c = 0; c < 4; ++c) {
            sx[c] += xa[c]; sy[c] += ya[c];
            sxx[c] += xa[c]*xa[c]; syy[c] += ya[c]*ya[c]; sxy[c] += xa[c]*ya[c];
        }
        if (last) {
            float xe = X[(size_t)rr * F_STRIDE + 1024];
            float ye = Y[(size_t)rr * F_STRIDE + 1024];
            s5[0] += xe; s5[1] += ye; s5[2] += xe*xe; s5[3] += ye*ye; s5[4] += xe*ye;
        }
    }

    float4 ax, ay, bx, by; float a5x=0, a5y=0, b5x=0, b5y=0;
    ax = *(const float4*)(X + (size_t)(t_begin + 3) * F_STRIDE + fv);
    ay = *(const float4*)(Y + (size_t)(t_begin + 3) * F_STRIDE + fv);
    bx = *(const float4*)(X + (size_t)(t_begin - 3) * F_STRIDE + fv);
    by = *(const float4*)(Y + (size_t)(t_begin - 3) * F_STRIDE + fv);
    if (last) {
        a5x = X[(size_t)(t_begin + 3) * F_STRIDE + 1024];
        a5y = Y[(size_t)(t_begin + 3) * F_STRIDE + 1024];
        b5x = X[(size_t)(t_begin - 3) * F_STRIDE + 1024];
        b5y = Y[(size_t)(t_begin - 3) * F_STRIDE + 1024];
    }

    const int fo = 3 + (tid << 2);

    for (int t = t_begin; t < t_end_; ++t) {
        {
            float xa[4] = {ax.x, ax.y, ax.z, ax.w}, ya[4] = {ay.x, ay.y, ay.z, ay.w};
            #pragma unroll
            for (int c = 0; c < 4; ++c) {
                sx[c] += xa[c]; sy[c] += ya[c];
                sxx[c] += xa[c]*xa[c]; syy[c] += ya[c]*ya[c]; sxy[c] += xa[c]*ya[c];
                int p = 5 * tid + c;
                csx[p] = sx[c]; csy[p] = sy[c];
                csxx[p] = sxx[c]; csyy[p] = syy[c]; csxy[p] = sxy[c];
            }
            if (last) {
                s5[0] += a5x; s5[1] += a5y; s5[2] += a5x*a5x; s5[3] += a5y*a5y; s5[4] += a5x*a5y;
                csx[1280] = s5[0]; csy[1280] = s5[1];
                csxx[1280] = s5[2]; csyy[1280] = s5[3]; csxy[1280] = s5[4];
            }
        }
        __syncthreads();

        {
            float xa[4] = {bx.x, bx.y, bx.z, bx.w}, ya[4] = {by.x, by.y, by.z, by.w};
            #pragma unroll
            for (int c = 0; c < 4; ++c) {
                sx[c] -= xa[c]; sy[c] -= ya[c];
                sxx[c] -= xa[c]*xa[c]; syy[c] -= ya[c]*ya[c]; sxy[c] -= xa[c]*ya[c];
            }
            if (last) {
                s5[0] -= b5x; s5[1] -= b5y; s5[2] -= b5x*b5x; s5[3] -= b5y*b5y; s5[4] -= b5x*b5y;
            }
        }
        if (t + 1 < t_end_) {
            ax = *(const float4*)(X + (size_t)(t + 4) * F_STRIDE + fv);
            ay = *(const float4*)(Y + (size_t)(t + 4) * F_STRIDE + fv);
            bx = *(const float4*)(X + (size_t)(t - 2) * F_STRIDE + fv);
            by = *(const float4*)(Y + (size_t)(t - 2) * F_STRIDE + fv);
            if (last) {
                a5x = X[(size_t)(t + 4) * F_STRIDE + 1024];
                a5y = Y[(size_t)(t + 4) * F_STRIDE + 1024];
                b5x = X[(size_t)(t - 2) * F_STRIDE + 1024];
                b5y = Y[(size_t)(t - 2) * F_STRIDE + 1024];
            }
        }

        if (tid < 255) {
            float tx[10], ty[10], txx[10], tyy[10], txy[10];
            #pragma unroll
            for (int d = 0; d < 10; ++d) {
                int p = 5 * tid + d + (d >> 2);
                tx[d] = csx[p]; ty[d] = csy[p];
                txx[d] = csxx[p]; tyy[d] = csyy[p]; txy[d] = csxy[p];
            }
            float wx  = tx[0]+tx[1]+tx[2]+tx[3]+tx[4]+tx[5]+tx[6];
            float wy  = ty[0]+ty[1]+ty[2]+ty[3]+ty[4]+ty[5]+ty[6];
            float wxx = txx[0]+txx[1]+txx[2]+txx[3]+txx[4]+txx[5]+txx[6];
            float wyy = tyy[0]+tyy[1]+tyy[2]+tyy[3]+tyy[4]+tyy[5]+tyy[6];
            float wxy = txy[0]+txy[1]+txy[2]+txy[3]+txy[4]+txy[5]+txy[6];
            #pragma unroll
            for (int c = 0; c < 4; ++c) {
                if (fo + c <= 1021) {
                    float ux  = wx * inv49, uy  = wy * inv49;
                    float uxx = wxx * inv49, uyy = wyy * inv49, uxy = wxy * inv49;
                    float vx  = COV_NORM_ * (uxx - ux * ux);
                    float vy  = COV_NORM_ * (uyy - uy * uy);
                    float vxy = COV_NORM_ * (uxy - ux * uy);
                    float Sv = ((2.f * ux * uy + C1_) * (2.f * vxy + C2_)) /
                               ((ux * ux + uy * uy + C1_) * (vx + vy + C2_));
                    acc += (double)Sv;
                }
                if (c < 3) {
                    wx  += tx[c+7]  - tx[c];
                    wy  += ty[c+7]  - ty[c];
                    wxx += txx[c+7] - txx[c];
                    wyy += tyy[c+7] - tyy[c];
                    wxy += txy[c+7] - txy[c];
                }
            }
        }
        __syncthreads();
    }

    red[tid] = acc;
    __syncthreads();
    for (int off = 128; off > 0; off >>= 1) {
        if (tid < off) red[tid] += red[tid + off];
        __syncthreads();
    }
    if (tid == 0) {
        atomicAdd(&out[ch], (float)(red[0] / (395.0 * 1019.0)));
    }
}

extern "C" void kernel_launch(void* const* d_in, const int* in_sizes, int n_in,
                              void* d_out, int out_size, void* d_ws, size_t ws_size,
                              hipStream_t stream) {
    const float* x0 = (const float*)d_in[0];   // output
    const float* x1 = (const float*)d_in[1];   // target
    float* out = (float*)d_out;
    float* ws  = (float*)d_ws;

    const size_t table_bytes  = (size_t)SPEC_OFF * sizeof(float);
    const size_t per_ch_bytes = (size_t)2 * T_FRAMES * F_STRIDE * sizeof(float);
    int G = (int)((ws_size - table_bytes) / per_ch_bytes);
    if (G > N_CH) G = N_CH;
    if (G < 1)    G = 1;

    init_tables_kernel<<<dim3(16), dim3(256), 0, stream>>>(ws, out);

    for (int ch0 = 0; ch0 < N_CH; ch0 += G) {
        const int nch = (N_CH - ch0 < G) ? (N_CH - ch0) : G;

        if (nch == 64) {
            stft_mag_kernel<<<dim3(201 * 128), dim3(128), 0, stream>>>(x0, x1, ws, ch0, nch, 1);
        } else {
            stft_mag_kernel<<<dim3(402, nch), dim3(128), 0, stream>>>(x0, x1, ws, ch0, nch, 0);
        }

        dim3 g2(N_CHUNKS, nch);
        ssim_kernel<<<g2, 256, 0, stream>>>(ws, out, ch0, nch);
    }
}

// Round 8
// 369.156 us; speedup vs baseline: 1.3870x; 1.3870x over previous
//
#include <hip/hip_runtime.h>
#include <math.h>

#ifndef M_PI
#define M_PI 3.14159265358979323846
#endif

constexpr int S_LEN    = 176400;
constexpr int NFFT     = 2048;
constexpr int NC       = 1024;
constexpr int HOP_     = 441;
constexpr int T_FRAMES = 401;
constexpr int F_BINS   = 1025;
constexpr int F_STRIDE = 1028;     // fp32 spec row stride (16B aligned)
constexpr int N_CH     = 64;
constexpr float EPS_   = 1e-8f;
constexpr float C1_    = 0.0004f;
constexpr float C2_    = 0.0036f;
constexpr float COV_NORM_ = 49.0f / 48.0f;

// workspace float offsets
constexpr int WIN_OFF  = 0;        // float[2048] hann window
constexpr int TWG_OFF  = 2048;     // float2[768]  tw[e] = exp(-2pi i e/1024)
constexpr int UTW_OFF  = 3584;     // float2[1025] exp(-i pi r/1024)
constexpr int SPEC_OFF = 5696;
constexpr int RPB_     = 10;
constexpr int N_CHUNKS = 40;

// LDS bank swizzle: phys(a) = a ^ ((a>>2)&15).  Bijective on [0,1024).
// For float2 (b64) accesses, every pattern used below (pack writes, stage reads
// b+256k, stage-i writes q+4*ps+j*s for s=1..256, unpack reads +/-r) yields 16
// distinct values mod 16 per 16 consecutive lanes -> conflict-free (verified
// per-pattern by the GF(2) triangular-invertibility of the low-nibble map).
__device__ __forceinline__ int phys(int i) { return i ^ ((i >> 2) & 15); }

__device__ __forceinline__ float2 cadd(float2 a, float2 b){ return make_float2(a.x+b.x, a.y+b.y); }
__device__ __forceinline__ float2 csub(float2 a, float2 b){ return make_float2(a.x-b.x, a.y-b.y); }
__device__ __forceinline__ float2 cmul(float2 a, float2 b){ return make_float2(a.x*b.x-a.y*b.y, a.x*b.y+a.y*b.x); }

__global__ __launch_bounds__(256) void init_tables_kernel(float* __restrict__ ws, float* __restrict__ out) {
    const int idx = blockIdx.x * 256 + threadIdx.x;
    if (idx < 64) out[idx] = 0.0f;
    if (idx < NFFT) {
        ws[WIN_OFF + idx] = 0.5f - 0.5f * cosf((float)(2.0 * M_PI / NFFT) * (float)idx);
    }
    if (idx < 768) {
        float ang = -2.0f * (float)M_PI * (float)idx / (float)NC;
        float s, c; sincosf(ang, &s, &c);
        ws[TWG_OFF + 2*idx] = c; ws[TWG_OFF + 2*idx+1] = s;
    }
    if (idx < F_BINS) {
        float ang = -(float)M_PI * (float)idx / (float)NC;
        float s, c; sincosf(ang, &s, &c);
        ws[UTW_OFF + 2*idx] = c; ws[UTW_OFF + 2*idx+1] = s;
    }
}

// Block-wide 1024-pt complex radix-4 Stockham (R2 structure: 214us, VALU 93%),
// with conflict-free XOR bank swizzle replacing the conflicted pad, global
// (L1-cached) twiddles replacing LDS staging, and XCD-aware channel swizzle.
// 16 KB LDS/block, 256 threads -> 8 blocks/CU (thread-capped, 32 waves).
__global__ __launch_bounds__(256, 8) void stft_mag_kernel(
    const float* __restrict__ x0, const float* __restrict__ x1,
    float* __restrict__ ws, int ch0, int nch, int swizzle)
{
    __shared__ float2 bufA[NC];
    __shared__ float2 bufB[NC];

    const int tid = threadIdx.x;

    int ch, which, t;
    if (swizzle) {
        int g = blockIdx.x;
        ch    = ch0 + (g & 7) * 8 + ((g >> 3) & 7);
        which = (g >> 6) & 1;
        t     = g >> 7;
    } else {
        int bx = blockIdx.x;
        which = bx / T_FRAMES;
        t     = bx - which * T_FRAMES;
        ch    = ch0 + blockIdx.y;
    }

    const float* __restrict__ xin = (which ? x1 : x0) + (size_t)ch * S_LEN;
    const float*  __restrict__ win = ws + WIN_OFF;
    const float2* __restrict__ twg = (const float2*)(ws + TWG_OFF);
    const float2* __restrict__ utw = (const float2*)(ws + UTW_OFF);

    // ---- pack: flat float index n over [0,2048); complex ci = n>>1 (swizzled)
    const int base = t * HOP_ - NFFT / 2;
    float* bufAf = (float*)bufA;
    #pragma unroll
    for (int k = 0; k < NFFT / 256; ++k) {
        int n = k * 256 + tid;
        int j = base + n;
        j = (j < 0) ? -j : j;
        j = (j >= S_LEN) ? (2 * S_LEN - 2 - j) : j;
        float v = xin[j] * win[n];
        int ci = n >> 1;
        bufAf[2 * phys(ci) + (n & 1)] = v;
    }
    __syncthreads();

    // ---- 5-stage radix-4 Stockham DIF (R2-verified butterfly/twiddles)
    float2* A = bufA;
    float2* B = bufB;
    #pragma unroll
    for (int i = 0; i < 5; ++i) {
        const int s_ = 1 << (2 * i);
        const int q  = tid & (s_ - 1);
        const int ps = tid - q;            // p * s

        float2 x0c = A[phys(tid)];
        float2 x1c = A[phys(tid + 256)];
        float2 x2c = A[phys(tid + 512)];
        float2 x3c = A[phys(tid + 768)];

        float2 t0 = cadd(x0c, x2c);
        float2 t1 = csub(x0c, x2c);
        float2 t2 = cadd(x1c, x3c);
        float2 t3 = csub(x1c, x3c);

        float2 y0 = cadd(t0, t2);
        float2 y2 = csub(t0, t2);
        float2 y1 = make_float2(t1.x + t3.y, t1.y - t3.x);   // t1 - i*t3
        float2 y3 = make_float2(t1.x - t3.y, t1.y + t3.x);   // t1 + i*t3

        float2 w1 = twg[ps];
        float2 w2 = twg[2 * ps];
        float2 w3 = twg[3 * ps];

        float2 z1 = cmul(y1, w1);
        float2 z2 = cmul(y2, w2);
        float2 z3 = cmul(y3, w3);

        const int o = q + 4 * ps;
        B[phys(o)]          = y0;
        B[phys(o + s_)]     = z1;
        B[phys(o + 2 * s_)] = z2;
        B[phys(o + 3 * s_)] = z3;
        __syncthreads();
        float2* tmp = A; A = B; B = tmp;
    }

    // ---- real-FFT unpack + magnitude + fp32 coalesced stores
    float* __restrict__ sout =
        ws + SPEC_OFF + ((size_t)which * nch + (size_t)(ch - ch0)) * (size_t)T_FRAMES * F_STRIDE
                      + (size_t)t * F_STRIDE;
    #pragma unroll
    for (int k = 0; k < 5; ++k) {
        int r = k * 256 + tid;
        if (k < 4 || tid == 0) {
            float2 Zr = A[phys(r & (NC - 1))];
            float2 Zn = A[phys((NC - r) & (NC - 1))];
            float Ex = 0.5f * (Zr.x + Zn.x);
            float Ey = 0.5f * (Zr.y - Zn.y);
            float Ox = 0.5f * (Zr.y + Zn.y);
            float Oy = 0.5f * (Zn.x - Zr.x);
            float2 wu = utw[r];
            float Xx = Ex + wu.x * Ox - wu.y * Oy;
            float Xy = Ey + wu.x * Oy + wu.y * Ox;
            sout[r] = sqrtf(fmaxf(Xx * Xx + Xy * Xy, EPS_));
        }
    }
}

// SSIM (proven R5/R7): thread owns 4 cols; float4 global loads; rolling vertical
// sums; 5 scalar LDS arrays with lane stride 5 -> conflict-free.
__global__ __launch_bounds__(256) void ssim_kernel(
    const float* __restrict__ ws, float* __restrict__ out,
    int ch0, int nch)
{
    __shared__ float csx[1284], csy[1284], csxx[1284], csyy[1284], csxy[1284];
    __shared__ double red[256];

    const int tid = threadIdx.x;
    const int cg  = blockIdx.y;
    const int ch  = ch0 + cg;
    const float* __restrict__ spec = ws + SPEC_OFF;
    const size_t per_ch = (size_t)T_FRAMES * F_STRIDE;
    const float* __restrict__ X = spec + (size_t)cg * per_ch;
    const float* __restrict__ Y = spec + ((size_t)nch + cg) * per_ch;

    const int t_begin = 3 + blockIdx.x * RPB_;
    const int t_end_  = min(t_begin + RPB_, T_FRAMES - 3);

    const int fv = tid << 2;
    const bool last = (tid == 255);
    const float inv49 = 1.0f / 49.0f;
    double acc = 0.0;

    float sx[4] = {0,0,0,0}, sy[4] = {0,0,0,0}, sxx[4] = {0,0,0,0},
          syy[4] = {0,0,0,0}, sxy[4] = {0,0,0,0};
    float s5[5] = {0,0,0,0,0};

    for (int rr = t_begin - 3; rr < t_begin + 3; ++rr) {
        float4 xv = *(const float4*)(X + (size_t)rr * F_STRIDE + fv);
        float4 yv = *(const float4*)(Y + (size_t)rr * F_STRIDE + fv);
        float xa[4] = {xv.x, xv.y, xv.z, xv.w}, ya[4] = {yv.x, yv.y, yv.z, yv.w};
        #pragma unroll
        for (int c = 0; c < 4; ++c) {
            sx[c] += xa[c]; sy[c] += ya[c];
            sxx[c] += xa[c]*xa[c]; syy[c] += ya[c]*ya[c]; sxy[c] += xa[c]*ya[c];
        }
        if (last) {
            float xe = X[(size_t)rr * F_STRIDE + 1024];
            float ye = Y[(size_t)rr * F_STRIDE + 1024];
            s5[0] += xe; s5[1] += ye; s5[2] += xe*xe; s5[3] += ye*ye; s5[4] += xe*ye;
        }
    }

    float4 ax, ay, bx, by; float a5x=0, a5y=0, b5x=0, b5y=0;
    ax = *(const float4*)(X + (size_t)(t_begin + 3) * F_STRIDE + fv);
    ay = *(const float4*)(Y + (size_t)(t_begin + 3) * F_STRIDE + fv);
    bx = *(const float4*)(X + (size_t)(t_begin - 3) * F_STRIDE + fv);
    by = *(const float4*)(Y + (size_t)(t_begin - 3) * F_STRIDE + fv);
    if (last) {
        a5x = X[(size_t)(t_begin + 3) * F_STRIDE + 1024];
        a5y = Y[(size_t)(t_begin + 3) * F_STRIDE + 1024];
        b5x = X[(size_t)(t_begin - 3) * F_STRIDE + 1024];
        b5y = Y[(size_t)(t_begin - 3) * F_STRIDE + 1024];
    }

    const int fo = 3 + (tid << 2);

    for (int t = t_begin; t < t_end_; ++t) {
        {
            float xa[4] = {ax.x, ax.y, ax.z, ax.w}, ya[4] = {ay.x, ay.y, ay.z, ay.w};
            #pragma unroll
            for (int c = 0; c < 4; ++c) {
                sx[c] += xa[c]; sy[c] += ya[c];
                sxx[c] += xa[c]*xa[c]; syy[c] += ya[c]*ya[c]; sxy[c] += xa[c]*ya[c];
                int p = 5 * tid + c;
                csx[p] = sx[c]; csy[p] = sy[c];
                csxx[p] = sxx[c]; csyy[p] = syy[c]; csxy[p] = sxy[c];
            }
            if (last) {
                s5[0] += a5x; s5[1] += a5y; s5[2] += a5x*a5x; s5[3] += a5y*a5y; s5[4] += a5x*a5y;
                csx[1280] = s5[0]; csy[1280] = s5[1];
                csxx[1280] = s5[2]; csyy[1280] = s5[3]; csxy[1280] = s5[4];
            }
        }
        __syncthreads();

        {
            float xa[4] = {bx.x, bx.y, bx.z, bx.w}, ya[4] = {by.x, by.y, by.z, by.w};
            #pragma unroll
            for (int c = 0; c < 4; ++c) {
                sx[c] -= xa[c]; sy[c] -= ya[c];
                sxx[c] -= xa[c]*xa[c]; syy[c] -= ya[c]*ya[c]; sxy[c] -= xa[c]*ya[c];
            }
            if (last) {
                s5[0] -= b5x; s5[1] -= b5y; s5[2] -= b5x*b5x; s5[3] -= b5y*b5y; s5[4] -= b5x*b5y;
            }
        }
        if (t + 1 < t_end_) {
            ax = *(const float4*)(X + (size_t)(t + 4) * F_STRIDE + fv);
            ay = *(const float4*)(Y + (size_t)(t + 4) * F_STRIDE + fv);
            bx = *(const float4*)(X + (size_t)(t - 2) * F_STRIDE + fv);
            by = *(const float4*)(Y + (size_t)(t - 2) * F_STRIDE + fv);
            if (last) {
                a5x = X[(size_t)(t + 4) * F_STRIDE + 1024];
                a5y = Y[(size_t)(t + 4) * F_STRIDE + 1024];
                b5x = X[(size_t)(t - 2) * F_STRIDE + 1024];
                b5y = Y[(size_t)(t - 2) * F_STRIDE + 1024];
            }
        }

        if (tid < 255) {
            float tx[10], ty[10], txx[10], tyy[10], txy[10];
            #pragma unroll
            for (int d = 0; d < 10; ++d) {
                int p = 5 * tid + d + (d >> 2);
                tx[d] = csx[p]; ty[d] = csy[p];
                txx[d] = csxx[p]; tyy[d] = csyy[p]; txy[d] = csxy[p];
            }
            float wx  = tx[0]+tx[1]+tx[2]+tx[3]+tx[4]+tx[5]+tx[6];
            float wy  = ty[0]+ty[1]+ty[2]+ty[3]+ty[4]+ty[5]+ty[6];
            float wxx = txx[0]+txx[1]+txx[2]+txx[3]+txx[4]+txx[5]+txx[6];
            float wyy = tyy[0]+tyy[1]+tyy[2]+tyy[3]+tyy[4]+tyy[5]+tyy[6];
            float wxy = txy[0]+txy[1]+txy[2]+txy[3]+txy[4]+txy[5]+txy[6];
            #pragma unroll
            for (int c = 0; c < 4; ++c) {
                if (fo + c <= 1021) {
                    float ux  = wx * inv49, uy  = wy * inv49;
                    float uxx = wxx * inv49, uyy = wyy * inv49, uxy = wxy * inv49;
                    float vx  = COV_NORM_ * (uxx - ux * ux);
                    float vy  = COV_NORM_ * (uyy - uy * uy);
                    float vxy = COV_NORM_ * (uxy - ux * uy);
                    float Sv = ((2.f * ux * uy + C1_) * (2.f * vxy + C2_)) /
                               ((ux * ux + uy * uy + C1_) * (vx + vy + C2_));
                    acc += (double)Sv;
                }
                if (c < 3) {
                    wx  += tx[c+7]  - tx[c];
                    wy  += ty[c+7]  - ty[c];
                    wxx += txx[c+7] - txx[c];
                    wyy += tyy[c+7] - tyy[c];
                    wxy += txy[c+7] - txy[c];
                }
            }
        }
        __syncthreads();
    }

    red[tid] = acc;
    __syncthreads();
    for (int off = 128; off > 0; off >>= 1) {
        if (tid < off) red[tid] += red[tid + off];
        __syncthreads();
    }
    if (tid == 0) {
        atomicAdd(&out[ch], (float)(red[0] / (395.0 * 1019.0)));
    }
}

extern "C" void kernel_launch(void* const* d_in, const int* in_sizes, int n_in,
                              void* d_out, int out_size, void* d_ws, size_t ws_size,
                              hipStream_t stream) {
    const float* x0 = (const float*)d_in[0];   // output
    const float* x1 = (const float*)d_in[1];   // target
    float* out = (float*)d_out;
    float* ws  = (float*)d_ws;

    const size_t table_bytes  = (size_t)SPEC_OFF * sizeof(float);
    const size_t per_ch_bytes = (size_t)2 * T_FRAMES * F_STRIDE * sizeof(float);
    int G = (int)((ws_size - table_bytes) / per_ch_bytes);
    if (G > N_CH) G = N_CH;
    if (G < 1)    G = 1;

    init_tables_kernel<<<dim3(16), dim3(256), 0, stream>>>(ws, out);

    for (int ch0 = 0; ch0 < N_CH; ch0 += G) {
        const int nch = (N_CH - ch0 < G) ? (N_CH - ch0) : G;

        if (nch == 64) {
            stft_mag_kernel<<<dim3(T_FRAMES * 128), dim3(256), 0, stream>>>(x0, x1, ws, ch0, nch, 1);
        } else {
            stft_mag_kernel<<<dim3(2 * T_FRAMES, nch), dim3(256), 0, stream>>>(x0, x1, ws, ch0, nch, 0);
        }

        dim3 g2(N_CHUNKS, nch);
        ssim_kernel<<<g2, 256, 0, stream>>>(ws, out, ch0, nch);
    }
}